// Round 5
// baseline (289.444 us; speedup 1.0000x reference)
//
#include <hip/hip_runtime.h>
#include <hip/hip_bf16.h>

#define EPS 1e-5f

// ---- workspace layout (float offsets) ----
#define OFF_ABAR 0          // 128*64*72   = 589824 floats
#define OFF_U    589824     // 128*64*256  = 2097152
#define OFF_V    2686976    // 2097152
#define OFF_PART 4784128    // 2048*256    = 524288  -> total 5308416 fl = 21.2 MB

__device__ __forceinline__ float elu(float z) {
    return z > 0.f ? z : __expf(z) - 1.f;
}

// K1: fused split-embedding + LayerNorm over (N,E) per batch.
__global__ __launch_bounds__(256) void k_embed_ln0(
    const float* __restrict__ xa, const float* __restrict__ xb,
    const float* __restrict__ Wa, const float* __restrict__ ba,
    const float* __restrict__ Wb, const float* __restrict__ bb,
    const float* __restrict__ g0, const float* __restrict__ b0,
    float* __restrict__ abar) {
    int b = blockIdx.x;
    int tid = threadIdx.x;
    float vals[18];
    float s1 = 0.f, s2 = 0.f;
    for (int m = 0; m < 18; ++m) {
        int k = tid + 256 * m;
        int e = k % 72;
        int n = k / 72;
        float acc;
        if (n < 32) {
            acc = ba[e];
            const float* x = xa + (b * 32 + n) * 23;
            #pragma unroll
            for (int d = 0; d < 23; ++d) acc = fmaf(x[d], Wa[d * 72 + e], acc);
        } else {
            acc = bb[e];
            const float* x = xb + (b * 32 + (n - 32)) * 13;
            #pragma unroll
            for (int d = 0; d < 13; ++d) acc = fmaf(x[d], Wb[d * 72 + e], acc);
        }
        vals[m] = acc;
        s1 += acc;
        s2 = fmaf(acc, acc, s2);
    }
    #pragma unroll
    for (int off = 32; off >= 1; off >>= 1) {
        s1 += __shfl_xor(s1, off, 64);
        s2 += __shfl_xor(s2, off, 64);
    }
    __shared__ float r1[4], r2[4];
    int w = tid >> 6;
    if ((tid & 63) == 0) { r1[w] = s1; r2[w] = s2; }
    __syncthreads();
    float t1 = r1[0] + r1[1] + r1[2] + r1[3];
    float t2 = r2[0] + r2[1] + r2[2] + r2[3];
    float mean = t1 * (1.f / 4608.f);
    float var  = fmaf(-mean, mean, t2 * (1.f / 4608.f));
    float rsq  = rsqrtf(var + EPS);
    float* ab = abar + b * 4608;
    for (int m = 0; m < 18; ++m) {
        int k = tid + 256 * m;
        ab[k] = fmaf((vals[m] - mean) * rsq, g0[k], b0[k]);
    }
}

// K2: U = abar @ Wg[0:72,:] (+ b_g folded in), V = abar @ Wg[72:144,:].
__global__ __launch_bounds__(256) void k_uv(
    const float* __restrict__ abar, const float* __restrict__ Wg,
    const float* __restrict__ bg,
    float* __restrict__ U, float* __restrict__ V) {
    int blk = blockIdx.x;            // 512 blocks
    int b = blk >> 2;
    int q = blk & 3;                 // n-range [q*16, q*16+16)
    int h = threadIdx.x;
    __shared__ float sa[72 * 16];    // [e][n], 4.5 KB
    const float* src = abar + (b * 64 + q * 16) * 72;
    for (int k = threadIdx.x; k < 72 * 16; k += 256) {
        int e = k >> 4, n = k & 15;
        sa[k] = src[n * 72 + e];
    }
    __syncthreads();
    float u[16], v[16];
    #pragma unroll
    for (int n = 0; n < 16; ++n) { u[n] = 0.f; v[n] = 0.f; }
    for (int e = 0; e < 72; ++e) {
        float wu = Wg[e * 256 + h];
        float wv = Wg[(72 + e) * 256 + h];
        const float4* sp = (const float4*)&sa[e * 16];
        #pragma unroll
        for (int n4 = 0; n4 < 4; ++n4) {
            float4 s4 = sp[n4];
            u[n4*4+0] = fmaf(s4.x, wu, u[n4*4+0]); v[n4*4+0] = fmaf(s4.x, wv, v[n4*4+0]);
            u[n4*4+1] = fmaf(s4.y, wu, u[n4*4+1]); v[n4*4+1] = fmaf(s4.y, wv, v[n4*4+1]);
            u[n4*4+2] = fmaf(s4.z, wu, u[n4*4+2]); v[n4*4+2] = fmaf(s4.z, wv, v[n4*4+2]);
            u[n4*4+3] = fmaf(s4.w, wu, u[n4*4+3]); v[n4*4+3] = fmaf(s4.w, wv, v[n4*4+3]);
        }
    }
    float bgh = bg[h];
    int base = (b * 64 + q * 16) * 256 + h;
    #pragma unroll
    for (int n = 0; n < 16; ++n) {
        U[base + n * 256] = u[n] + bgh;   // b_g folded into U
        V[base + n * 256] = v[n];
    }
}

// K3 v3: one elu pass per element; E cached in LDS as bf16 (swizzled).
// grid = 2048 (128 b × 16 ic); block = 512 threads (8 waves); 4 i's per block.
// Phase A: thread (j = t>>3, oc = t&7) computes e = elu(u+v) for h = oc*4+32c
//   (c=0..7) in f32, in-lane s1/s2, 3-step shfl_xor over the 8-thread j-group,
//   writes e as bf16x4 (b64, bank-floor swizzle).
// Phase B: thread (p4 = t&63, jq = t>>6) reads b64 E-quads over 8 j's,
//   acc += e*rsq[j]; -sum(mr) folded in per thread. Block reduce over jq once.
__global__ __launch_bounds__(512, 8) void k_pair(
    const float* __restrict__ U, const float* __restrict__ V,
    float* __restrict__ part) {
    int blk = blockIdx.x;
    int b = blk >> 4, ic = blk & 15;
    int t = threadIdx.x;
    int j  = t >> 3;               // 0..63
    int oc = t & 7;
    __shared__ __align__(16) unsigned Ew[64 * 128];   // 32 KB bf16 E
    __shared__ float rsq_s[64], mr_s[64];
    float* sc = (float*)Ew;                            // aliased scratch [8][64][4]

    const float* __restrict__ Vrow  = V + (size_t)(b * 64 + j) * 256;
    const float* __restrict__ Ubase = U + (size_t)(b * 64) * 256;

    int p4 = t & 63;               // phase-B h-quad (h = 4*p4); lane index
    int jq = t >> 6;               // 0..7
    float acc0 = 0.f, acc1 = 0.f, acc2 = 0.f, acc3 = 0.f;

    for (int ii = 0; ii < 4; ++ii) {
        const float* __restrict__ Urow = Ubase + (size_t)(ic * 4 + ii) * 256;
        // ---- phase A ----
        float s1 = 0.f, s2 = 0.f;
        #pragma unroll
        for (int c = 0; c < 8; ++c) {
            int h = oc * 4 + c * 32;
            float4 v4 = *(const float4*)&Vrow[h];
            float4 u4 = *(const float4*)&Urow[h];
            float e0 = elu(u4.x + v4.x);
            float e1 = elu(u4.y + v4.y);
            float e2 = elu(u4.z + v4.z);
            float e3 = elu(u4.w + v4.w);
            s1 += (e0 + e1) + (e2 + e3);
            s2 = fmaf(e0, e0, fmaf(e1, e1, fmaf(e2, e2, fmaf(e3, e3, s2))));
            // pack high halves: w = [e_odd.hi16 : e_even.hi16] (bf16 truncate)
            unsigned w0 = __builtin_amdgcn_perm(__float_as_uint(e1), __float_as_uint(e0), 0x07060302u);
            unsigned w1 = __builtin_amdgcn_perm(__float_as_uint(e3), __float_as_uint(e2), 0x07060302u);
            int hw0  = oc * 2 + c * 16;                 // word index in row
            int addr = (j << 7) + (hw0 ^ (c << 1) ^ ((j & 7) << 1) ^ ((j & 1) << 4));
            *(uint2*)&Ew[addr] = make_uint2(w0, w1);
        }
        #pragma unroll
        for (int d = 1; d <= 4; d <<= 1) {
            s1 += __shfl_xor(s1, d, 64);
            s2 += __shfl_xor(s2, d, 64);
        }
        float mu  = s1 * (1.f / 256.f);
        float var = fmaf(-mu, mu, s2 * (1.f / 256.f));
        float rsq = rsqrtf(var + EPS);
        if (oc == 0) { rsq_s[j] = rsq; mr_s[j] = mu * rsq; }
        __syncthreads();
        // ---- phase B ----
        float mloc = 0.f;
        #pragma unroll
        for (int jj = 0; jj < 8; ++jj) {
            int jb = jq * 8 + jj;
            float r = rsq_s[jb];
            mloc += mr_s[jb];
            int hw = p4 * 2;
            int addr = (jb << 7) + (hw ^ (((hw >> 4) & 7) << 1) ^ ((jb & 7) << 1) ^ ((jb & 1) << 4));
            uint2 w = *(const uint2*)&Ew[addr];
            float f0 = __uint_as_float(w.x << 16);
            float f1 = __uint_as_float(w.x & 0xffff0000u);
            float f2 = __uint_as_float(w.y << 16);
            float f3 = __uint_as_float(w.y & 0xffff0000u);
            acc0 = fmaf(f0, r, acc0);
            acc1 = fmaf(f1, r, acc1);
            acc2 = fmaf(f2, r, acc2);
            acc3 = fmaf(f3, r, acc3);
        }
        acc0 -= mloc; acc1 -= mloc; acc2 -= mloc; acc3 -= mloc;
        __syncthreads();
    }
    // ---- block reduce over jq (scratch aliases Ew; all E reads done) ----
    *(float4*)&sc[(jq * 64 + p4) * 4] = make_float4(acc0, acc1, acc2, acc3);
    __syncthreads();
    if (t < 64) {
        float4 r = make_float4(0.f, 0.f, 0.f, 0.f);
        #pragma unroll
        for (int q = 0; q < 8; ++q) {
            float4 x = *(const float4*)&sc[(q * 64 + t) * 4];
            r.x += x.x; r.y += x.y; r.z += x.z; r.w += x.w;
        }
        *(float4*)&part[(size_t)blk * 256 + t * 4] = r;
    }
}

// K4: reduce 16 partials, apply lng_g / (4096*lng_b), 256x128 GEMM + elu.
__global__ __launch_bounds__(256) void k_out(
    const float* __restrict__ part,
    const float* __restrict__ lgg, const float* __restrict__ lgb,
    const float* __restrict__ Wf,  const float* __restrict__ bfb,
    float* __restrict__ out) {
    int b = blockIdx.x;
    int t = threadIdx.x;  // 256
    __shared__ float sh[256];
    __shared__ float ps[256];
    {
        float s = 0.f;
        #pragma unroll
        for (int k = 0; k < 16; ++k) s += part[(size_t)(b * 16 + k) * 256 + t];
        sh[t] = fmaf(lgg[t], s, 4096.f * lgb[t]);   // -sum(mr) already folded in
    }
    __syncthreads();
    int f = t & 127, half = t >> 7;
    float acc = 0.f;
    for (int h = half * 128; h < half * 128 + 128; ++h)
        acc = fmaf(sh[h], Wf[h * 128 + f], acc);
    ps[t] = acc;
    __syncthreads();
    if (t < 128) {
        float r = ps[t] + ps[t + 128] + bfb[t];
        out[b * 128 + t] = r > 0.f ? r : __expf(r) - 1.f;
    }
}

extern "C" void kernel_launch(void* const* d_in, const int* in_sizes, int n_in,
                              void* d_out, int out_size, void* d_ws, size_t ws_size,
                              hipStream_t stream) {
    const float* xa  = (const float*)d_in[0];
    const float* xb  = (const float*)d_in[1];
    const float* Wa  = (const float*)d_in[2];
    const float* ba  = (const float*)d_in[3];
    const float* Wb  = (const float*)d_in[4];
    const float* bb  = (const float*)d_in[5];
    const float* g0  = (const float*)d_in[6];
    const float* b0  = (const float*)d_in[7];
    const float* Wg  = (const float*)d_in[8];
    const float* bg  = (const float*)d_in[9];
    const float* lgg = (const float*)d_in[10];
    const float* lgb = (const float*)d_in[11];
    const float* Wf  = (const float*)d_in[12];
    const float* bfb = (const float*)d_in[13];
    float* out = (float*)d_out;

    float* ws   = (float*)d_ws;
    float* abar = ws + OFF_ABAR;
    float* U    = ws + OFF_U;
    float* V    = ws + OFF_V;
    float* part = ws + OFF_PART;

    k_embed_ln0<<<128, 256, 0, stream>>>(xa, xb, Wa, ba, Wb, bb, g0, b0, abar);
    k_uv<<<512, 256, 0, stream>>>(abar, Wg, bg, U, V);
    k_pair<<<2048, 512, 0, stream>>>(U, V, part);
    k_out<<<128, 256, 0, stream>>>(part, lgg, lgb, Wf, bfb, out);
}

// Round 6
// 161.288 us; speedup vs baseline: 1.7946x; 1.7946x over previous
//
#include <hip/hip_runtime.h>
#include <hip/hip_bf16.h>

#define EPS 1e-5f

// ---- workspace layout (float offsets) ----
#define OFF_ABAR 0          // 128*64*72   = 589824 floats
#define OFF_U    589824     // 128*64*256  = 2097152
#define OFF_V    2686976    // 2097152
#define OFF_PART 4784128    // 512*256     = 131072  -> total 4915200 fl = 19.7 MB

__device__ __forceinline__ float elu(float z) {
    return z > 0.f ? z : __expf(z) - 1.f;
}

// K1: fused split-embedding + LayerNorm over (N,E) per batch.
__global__ __launch_bounds__(256) void k_embed_ln0(
    const float* __restrict__ xa, const float* __restrict__ xb,
    const float* __restrict__ Wa, const float* __restrict__ ba,
    const float* __restrict__ Wb, const float* __restrict__ bb,
    const float* __restrict__ g0, const float* __restrict__ b0,
    float* __restrict__ abar) {
    int b = blockIdx.x;
    int tid = threadIdx.x;
    float vals[18];
    float s1 = 0.f, s2 = 0.f;
    for (int m = 0; m < 18; ++m) {
        int k = tid + 256 * m;
        int e = k % 72;
        int n = k / 72;
        float acc;
        if (n < 32) {
            acc = ba[e];
            const float* x = xa + (b * 32 + n) * 23;
            #pragma unroll
            for (int d = 0; d < 23; ++d) acc = fmaf(x[d], Wa[d * 72 + e], acc);
        } else {
            acc = bb[e];
            const float* x = xb + (b * 32 + (n - 32)) * 13;
            #pragma unroll
            for (int d = 0; d < 13; ++d) acc = fmaf(x[d], Wb[d * 72 + e], acc);
        }
        vals[m] = acc;
        s1 += acc;
        s2 = fmaf(acc, acc, s2);
    }
    #pragma unroll
    for (int off = 32; off >= 1; off >>= 1) {
        s1 += __shfl_xor(s1, off, 64);
        s2 += __shfl_xor(s2, off, 64);
    }
    __shared__ float r1[4], r2[4];
    int w = tid >> 6;
    if ((tid & 63) == 0) { r1[w] = s1; r2[w] = s2; }
    __syncthreads();
    float t1 = r1[0] + r1[1] + r1[2] + r1[3];
    float t2 = r2[0] + r2[1] + r2[2] + r2[3];
    float mean = t1 * (1.f / 4608.f);
    float var  = fmaf(-mean, mean, t2 * (1.f / 4608.f));
    float rsq  = rsqrtf(var + EPS);
    float* ab = abar + b * 4608;
    for (int m = 0; m < 18; ++m) {
        int k = tid + 256 * m;
        ab[k] = fmaf((vals[m] - mean) * rsq, g0[k], b0[k]);
    }
}

// K2: U = abar @ Wg[0:72,:] (+ b_g folded in), V = abar @ Wg[72:144,:].
__global__ __launch_bounds__(256) void k_uv(
    const float* __restrict__ abar, const float* __restrict__ Wg,
    const float* __restrict__ bg,
    float* __restrict__ U, float* __restrict__ V) {
    int blk = blockIdx.x;            // 512 blocks
    int b = blk >> 2;
    int q = blk & 3;                 // n-range [q*16, q*16+16)
    int h = threadIdx.x;
    __shared__ float sa[72 * 16];    // [e][n], 4.5 KB
    const float* src = abar + (b * 64 + q * 16) * 72;
    for (int k = threadIdx.x; k < 72 * 16; k += 256) {
        int e = k >> 4, n = k & 15;
        sa[k] = src[n * 72 + e];
    }
    __syncthreads();
    float u[16], v[16];
    #pragma unroll
    for (int n = 0; n < 16; ++n) { u[n] = 0.f; v[n] = 0.f; }
    for (int e = 0; e < 72; ++e) {
        float wu = Wg[e * 256 + h];
        float wv = Wg[(72 + e) * 256 + h];
        const float4* sp = (const float4*)&sa[e * 16];
        #pragma unroll
        for (int n4 = 0; n4 < 4; ++n4) {
            float4 s4 = sp[n4];
            u[n4*4+0] = fmaf(s4.x, wu, u[n4*4+0]); v[n4*4+0] = fmaf(s4.x, wv, v[n4*4+0]);
            u[n4*4+1] = fmaf(s4.y, wu, u[n4*4+1]); v[n4*4+1] = fmaf(s4.y, wv, v[n4*4+1]);
            u[n4*4+2] = fmaf(s4.z, wu, u[n4*4+2]); v[n4*4+2] = fmaf(s4.z, wv, v[n4*4+2]);
            u[n4*4+3] = fmaf(s4.w, wu, u[n4*4+3]); v[n4*4+3] = fmaf(s4.w, wv, v[n4*4+3]);
        }
    }
    float bgh = bg[h];
    int base = (b * 64 + q * 16) * 256 + h;
    #pragma unroll
    for (int n = 0; n < 16; ++n) {
        U[base + n * 256] = u[n] + bgh;   // b_g folded into U
        V[base + n * 256] = v[n];
    }
}

// K3 v4: elu exactly once, E lives in registers only.
// grid = 512 (128 b × 2 i-halves × 2 j-halves); block = 512 threads (8 waves).
// Thread (j32 = t>>4, hc = t&15) owns column j = j0+j32 and 16 h's
// (h = hc*4 + 64c + k, c<4, k<4 — dense float4 groups). V-slice in registers.
// U[b, i-half] (32 KB) staged once in LDS; reads are 16-lane-dense float4
// (4-way same-address broadcast across j-groups + 2-way bank alias = free).
// Per i: e[16] once in f32; s1/s2 via 4 shfl_xor over the 16-lane h-group;
// mu/rsq computed per-lane (redundant, free); acc[16] += e*rsq; -mr folded
// per-thread into macc. Block-reduce over j32 at the end (LDS reused).
__global__ __launch_bounds__(512, 4) void k_pair(
    const float* __restrict__ U, const float* __restrict__ V,
    float* __restrict__ part) {
    int blk = blockIdx.x;
    int b  = blk >> 2;
    int ih = (blk >> 1) & 1;
    int jh = blk & 1;
    int t  = threadIdx.x;
    int j32 = t >> 4;             // 0..31
    int hc  = t & 15;             // 0..15

    __shared__ float Us[32 * 256];   // 32 KB; reused as reduce scratch

    // stage U[b, ih*32 .. +32) — coalesced float4
    const float* Ug = U + (size_t)(b * 64 + ih * 32) * 256;
    #pragma unroll
    for (int r = 0; r < 4; ++r) {
        int k = t * 4 + r * 2048;
        *(float4*)&Us[k] = *(const float4*)&Ug[k];
    }

    // V-slice into registers (coalesced: 16 consecutive lanes read dense rows)
    const float* Vrow = V + (size_t)(b * 64 + jh * 32 + j32) * 256;
    float v[16];
    #pragma unroll
    for (int c = 0; c < 4; ++c) {
        float4 v4 = *(const float4*)&Vrow[hc * 4 + 64 * c];
        v[c*4+0] = v4.x; v[c*4+1] = v4.y; v[c*4+2] = v4.z; v[c*4+3] = v4.w;
    }

    __syncthreads();

    float acc[16];
    #pragma unroll
    for (int k = 0; k < 16; ++k) acc[k] = 0.f;
    float macc = 0.f;

    for (int i = 0; i < 32; ++i) {
        const float* ur = &Us[i * 256];
        float e[16];
        float s1 = 0.f, s2 = 0.f;
        #pragma unroll
        for (int c = 0; c < 4; ++c) {
            float4 u4 = *(const float4*)&ur[hc * 4 + 64 * c];
            float e0 = elu(u4.x + v[c*4+0]);
            float e1 = elu(u4.y + v[c*4+1]);
            float e2 = elu(u4.z + v[c*4+2]);
            float e3 = elu(u4.w + v[c*4+3]);
            e[c*4+0] = e0; e[c*4+1] = e1; e[c*4+2] = e2; e[c*4+3] = e3;
            s1 += (e0 + e1) + (e2 + e3);
            s2 = fmaf(e0, e0, fmaf(e1, e1, fmaf(e2, e2, fmaf(e3, e3, s2))));
        }
        // reduce over the 16-lane h-group (same j)
        #pragma unroll
        for (int d = 1; d <= 8; d <<= 1) {
            s1 += __shfl_xor(s1, d, 64);
            s2 += __shfl_xor(s2, d, 64);
        }
        float mu  = s1 * (1.f / 256.f);
        float var = fmaf(-mu, mu, s2 * (1.f / 256.f));
        float rsq = rsqrtf(var + EPS);
        macc += mu * rsq;
        #pragma unroll
        for (int k = 0; k < 16; ++k) acc[k] = fmaf(e[k], rsq, acc[k]);
    }
    #pragma unroll
    for (int k = 0; k < 16; ++k) acc[k] -= macc;

    // block reduce over j32 (reuse Us: [j32][256])
    __syncthreads();
    #pragma unroll
    for (int c = 0; c < 4; ++c)
        *(float4*)&Us[j32 * 256 + hc * 4 + 64 * c] =
            make_float4(acc[c*4+0], acc[c*4+1], acc[c*4+2], acc[c*4+3]);
    __syncthreads();
    if (t < 256) {
        float r = 0.f;
        #pragma unroll
        for (int q = 0; q < 32; ++q) r += Us[q * 256 + t];
        part[(size_t)blk * 256 + t] = r;
    }
}

// K4: reduce 4 partials, apply lng_g / (4096 * lng_b), 256x128 GEMM + elu.
__global__ __launch_bounds__(128) void k_out(
    const float* __restrict__ part,
    const float* __restrict__ lgg, const float* __restrict__ lgb,
    const float* __restrict__ Wf,  const float* __restrict__ bfb,
    float* __restrict__ out) {
    int b = blockIdx.x;
    int f = threadIdx.x;  // 128
    __shared__ float sh[256];
    for (int h = f; h < 256; h += 128) {
        float s = part[(b * 4 + 0) * 256 + h] + part[(b * 4 + 1) * 256 + h]
                + part[(b * 4 + 2) * 256 + h] + part[(b * 4 + 3) * 256 + h];
        sh[h] = fmaf(lgg[h], s, 4096.f * lgb[h]);
    }
    __syncthreads();
    float acc = bfb[f];
    for (int h = 0; h < 256; ++h)
        acc = fmaf(sh[h], Wf[h * 128 + f], acc);
    float r = acc > 0.f ? acc : __expf(acc) - 1.f;
    out[b * 128 + f] = r;
}

extern "C" void kernel_launch(void* const* d_in, const int* in_sizes, int n_in,
                              void* d_out, int out_size, void* d_ws, size_t ws_size,
                              hipStream_t stream) {
    const float* xa  = (const float*)d_in[0];
    const float* xb  = (const float*)d_in[1];
    const float* Wa  = (const float*)d_in[2];
    const float* ba  = (const float*)d_in[3];
    const float* Wb  = (const float*)d_in[4];
    const float* bb  = (const float*)d_in[5];
    const float* g0  = (const float*)d_in[6];
    const float* b0  = (const float*)d_in[7];
    const float* Wg  = (const float*)d_in[8];
    const float* bg  = (const float*)d_in[9];
    const float* lgg = (const float*)d_in[10];
    const float* lgb = (const float*)d_in[11];
    const float* Wf  = (const float*)d_in[12];
    const float* bfb = (const float*)d_in[13];
    float* out = (float*)d_out;

    float* ws   = (float*)d_ws;
    float* abar = ws + OFF_ABAR;
    float* U    = ws + OFF_U;
    float* V    = ws + OFF_V;
    float* part = ws + OFF_PART;

    k_embed_ln0<<<128, 256, 0, stream>>>(xa, xb, Wa, ba, Wb, bb, g0, b0, abar);
    k_uv<<<512, 256, 0, stream>>>(abar, Wg, bg, U, V);
    k_pair<<<512, 512, 0, stream>>>(U, V, part);
    k_out<<<128, 128, 0, stream>>>(part, lgg, lgb, Wf, bfb, out);
}

// Round 7
// 156.260 us; speedup vs baseline: 1.8523x; 1.0322x over previous
//
#include <hip/hip_runtime.h>
#include <hip/hip_bf16.h>

#define EPS 1e-5f

// ---- workspace layout (float offsets) ----
#define OFF_ABAR 0          // 128*64*72   = 589824 floats
#define OFF_U    589824     // 128*64*256  = 2097152
#define OFF_V    2686976    // 2097152
#define OFF_PART 4784128    // 1024*256    = 262144  -> total 5046272 fl = 20.2 MB

__device__ __forceinline__ float elu(float z) {
    return z > 0.f ? z : __expf(z) - 1.f;
}

// K1: fused split-embedding + LayerNorm over (N,E) per batch.
__global__ __launch_bounds__(256) void k_embed_ln0(
    const float* __restrict__ xa, const float* __restrict__ xb,
    const float* __restrict__ Wa, const float* __restrict__ ba,
    const float* __restrict__ Wb, const float* __restrict__ bb,
    const float* __restrict__ g0, const float* __restrict__ b0,
    float* __restrict__ abar) {
    int b = blockIdx.x;
    int tid = threadIdx.x;
    float vals[18];
    float s1 = 0.f, s2 = 0.f;
    for (int m = 0; m < 18; ++m) {
        int k = tid + 256 * m;
        int e = k % 72;
        int n = k / 72;
        float acc;
        if (n < 32) {
            acc = ba[e];
            const float* x = xa + (b * 32 + n) * 23;
            #pragma unroll
            for (int d = 0; d < 23; ++d) acc = fmaf(x[d], Wa[d * 72 + e], acc);
        } else {
            acc = bb[e];
            const float* x = xb + (b * 32 + (n - 32)) * 13;
            #pragma unroll
            for (int d = 0; d < 13; ++d) acc = fmaf(x[d], Wb[d * 72 + e], acc);
        }
        vals[m] = acc;
        s1 += acc;
        s2 = fmaf(acc, acc, s2);
    }
    #pragma unroll
    for (int off = 32; off >= 1; off >>= 1) {
        s1 += __shfl_xor(s1, off, 64);
        s2 += __shfl_xor(s2, off, 64);
    }
    __shared__ float r1[4], r2[4];
    int w = tid >> 6;
    if ((tid & 63) == 0) { r1[w] = s1; r2[w] = s2; }
    __syncthreads();
    float t1 = r1[0] + r1[1] + r1[2] + r1[3];
    float t2 = r2[0] + r2[1] + r2[2] + r2[3];
    float mean = t1 * (1.f / 4608.f);
    float var  = fmaf(-mean, mean, t2 * (1.f / 4608.f));
    float rsq  = rsqrtf(var + EPS);
    float* ab = abar + b * 4608;
    for (int m = 0; m < 18; ++m) {
        int k = tid + 256 * m;
        ab[k] = fmaf((vals[m] - mean) * rsq, g0[k], b0[k]);
    }
}

// K2: U = abar @ Wg[0:72,:] (+ b_g folded in), V = abar @ Wg[72:144,:].
__global__ __launch_bounds__(256) void k_uv(
    const float* __restrict__ abar, const float* __restrict__ Wg,
    const float* __restrict__ bg,
    float* __restrict__ U, float* __restrict__ V) {
    int blk = blockIdx.x;            // 512 blocks
    int b = blk >> 2;
    int q = blk & 3;                 // n-range [q*16, q*16+16)
    int h = threadIdx.x;
    __shared__ float sa[72 * 16];    // [e][n], 4.5 KB
    const float* src = abar + (b * 64 + q * 16) * 72;
    for (int k = threadIdx.x; k < 72 * 16; k += 256) {
        int e = k >> 4, n = k & 15;
        sa[k] = src[n * 72 + e];
    }
    __syncthreads();
    float u[16], v[16];
    #pragma unroll
    for (int n = 0; n < 16; ++n) { u[n] = 0.f; v[n] = 0.f; }
    for (int e = 0; e < 72; ++e) {
        float wu = Wg[e * 256 + h];
        float wv = Wg[(72 + e) * 256 + h];
        const float4* sp = (const float4*)&sa[e * 16];
        #pragma unroll
        for (int n4 = 0; n4 < 4; ++n4) {
            float4 s4 = sp[n4];
            u[n4*4+0] = fmaf(s4.x, wu, u[n4*4+0]); v[n4*4+0] = fmaf(s4.x, wv, v[n4*4+0]);
            u[n4*4+1] = fmaf(s4.y, wu, u[n4*4+1]); v[n4*4+1] = fmaf(s4.y, wv, v[n4*4+1]);
            u[n4*4+2] = fmaf(s4.z, wu, u[n4*4+2]); v[n4*4+2] = fmaf(s4.z, wv, v[n4*4+2]);
            u[n4*4+3] = fmaf(s4.w, wu, u[n4*4+3]); v[n4*4+3] = fmaf(s4.w, wv, v[n4*4+3]);
        }
    }
    float bgh = bg[h];
    int base = (b * 64 + q * 16) * 256 + h;
    #pragma unroll
    for (int n = 0; n < 16; ++n) {
        U[base + n * 256] = u[n] + bgh;   // b_g folded into U
        V[base + n * 256] = v[n];
    }
}

// K3 v5: elu once, E in registers; 1024 blocks for full occupancy.
// grid = 1024 (128 b × 4 i-quarters × 2 j-halves); block = 512 threads.
// Thread (j32 = t>>4, hc = t&15) owns column j = jh*32+j32 and 16 h's
// (h = hc*4 + 64c + k). V-slice in registers; U[b, iq*16..+16) staged in LDS.
// Per i: e[16] once in f32; s1/s2 via 4 shfl_xor over the 16-lane h-group;
// mu/rsq per-lane; acc[16] += e*rsq; -mr folded per-thread. Block-reduce
// over j32 at the end (32 KB LDS scratch, reused).
__global__ __launch_bounds__(512, 4) void k_pair(
    const float* __restrict__ U, const float* __restrict__ V,
    float* __restrict__ part) {
    int blk = blockIdx.x;
    int b  = blk >> 3;
    int iq = (blk >> 1) & 3;
    int jh = blk & 1;
    int t  = threadIdx.x;
    int j32 = t >> 4;             // 0..31
    int hc  = t & 15;             // 0..15

    __shared__ float Us[32 * 256];   // 32 KB; first 16 KB = U tile, all = scratch

    // stage U[b, iq*16 .. +16) — coalesced float4 (4096 floats)
    const float* Ug = U + (size_t)(b * 64 + iq * 16) * 256;
    #pragma unroll
    for (int r = 0; r < 2; ++r) {
        int k = t * 4 + r * 2048;
        *(float4*)&Us[k] = *(const float4*)&Ug[k];
    }

    // V-slice into registers (16 consecutive lanes read dense rows)
    const float* Vrow = V + (size_t)(b * 64 + jh * 32 + j32) * 256;
    float v[16];
    #pragma unroll
    for (int c = 0; c < 4; ++c) {
        float4 v4 = *(const float4*)&Vrow[hc * 4 + 64 * c];
        v[c*4+0] = v4.x; v[c*4+1] = v4.y; v[c*4+2] = v4.z; v[c*4+3] = v4.w;
    }

    __syncthreads();

    float acc[16];
    #pragma unroll
    for (int k = 0; k < 16; ++k) acc[k] = 0.f;
    float macc = 0.f;

    for (int i = 0; i < 16; ++i) {
        const float* ur = &Us[i * 256];
        float e[16];
        float s1 = 0.f, s2 = 0.f;
        #pragma unroll
        for (int c = 0; c < 4; ++c) {
            float4 u4 = *(const float4*)&ur[hc * 4 + 64 * c];
            float e0 = elu(u4.x + v[c*4+0]);
            float e1 = elu(u4.y + v[c*4+1]);
            float e2 = elu(u4.z + v[c*4+2]);
            float e3 = elu(u4.w + v[c*4+3]);
            e[c*4+0] = e0; e[c*4+1] = e1; e[c*4+2] = e2; e[c*4+3] = e3;
            s1 += (e0 + e1) + (e2 + e3);
            s2 = fmaf(e0, e0, fmaf(e1, e1, fmaf(e2, e2, fmaf(e3, e3, s2))));
        }
        // reduce over the 16-lane h-group (same j)
        #pragma unroll
        for (int d = 1; d <= 8; d <<= 1) {
            s1 += __shfl_xor(s1, d, 64);
            s2 += __shfl_xor(s2, d, 64);
        }
        float mu  = s1 * (1.f / 256.f);
        float var = fmaf(-mu, mu, s2 * (1.f / 256.f));
        float rsq = rsqrtf(var + EPS);
        macc += mu * rsq;
        #pragma unroll
        for (int k = 0; k < 16; ++k) acc[k] = fmaf(e[k], rsq, acc[k]);
    }
    #pragma unroll
    for (int k = 0; k < 16; ++k) acc[k] -= macc;

    // block reduce over j32 (reuse Us: [j32][256])
    __syncthreads();
    #pragma unroll
    for (int c = 0; c < 4; ++c)
        *(float4*)&Us[j32 * 256 + hc * 4 + 64 * c] =
            make_float4(acc[c*4+0], acc[c*4+1], acc[c*4+2], acc[c*4+3]);
    __syncthreads();
    if (t < 256) {
        float r = 0.f;
        #pragma unroll
        for (int q = 0; q < 32; ++q) r += Us[q * 256 + t];
        part[(size_t)blk * 256 + t] = r;
    }
}

// K4: reduce 8 partials, apply lng_g / (4096 * lng_b), 256x128 GEMM + elu.
__global__ __launch_bounds__(128) void k_out(
    const float* __restrict__ part,
    const float* __restrict__ lgg, const float* __restrict__ lgb,
    const float* __restrict__ Wf,  const float* __restrict__ bfb,
    float* __restrict__ out) {
    int b = blockIdx.x;
    int f = threadIdx.x;  // 128
    __shared__ float sh[256];
    for (int h = f; h < 256; h += 128) {
        float s = 0.f;
        #pragma unroll
        for (int p = 0; p < 8; ++p) s += part[(size_t)(b * 8 + p) * 256 + h];
        sh[h] = fmaf(lgg[h], s, 4096.f * lgb[h]);
    }
    __syncthreads();
    float acc = bfb[f];
    for (int h = 0; h < 256; ++h)
        acc = fmaf(sh[h], Wf[h * 128 + f], acc);
    float r = acc > 0.f ? acc : __expf(acc) - 1.f;
    out[b * 128 + f] = r;
}

extern "C" void kernel_launch(void* const* d_in, const int* in_sizes, int n_in,
                              void* d_out, int out_size, void* d_ws, size_t ws_size,
                              hipStream_t stream) {
    const float* xa  = (const float*)d_in[0];
    const float* xb  = (const float*)d_in[1];
    const float* Wa  = (const float*)d_in[2];
    const float* ba  = (const float*)d_in[3];
    const float* Wb  = (const float*)d_in[4];
    const float* bb  = (const float*)d_in[5];
    const float* g0  = (const float*)d_in[6];
    const float* b0  = (const float*)d_in[7];
    const float* Wg  = (const float*)d_in[8];
    const float* bg  = (const float*)d_in[9];
    const float* lgg = (const float*)d_in[10];
    const float* lgb = (const float*)d_in[11];
    const float* Wf  = (const float*)d_in[12];
    const float* bfb = (const float*)d_in[13];
    float* out = (float*)d_out;

    float* ws   = (float*)d_ws;
    float* abar = ws + OFF_ABAR;
    float* U    = ws + OFF_U;
    float* V    = ws + OFF_V;
    float* part = ws + OFF_PART;

    k_embed_ln0<<<128, 256, 0, stream>>>(xa, xb, Wa, ba, Wb, bb, g0, b0, abar);
    k_uv<<<512, 256, 0, stream>>>(abar, Wg, bg, U, V);
    k_pair<<<1024, 512, 0, stream>>>(U, V, part);
    k_out<<<128, 128, 0, stream>>>(part, lgg, lgb, Wf, bfb, out);
}